// Round 1
// baseline (1152.802 us; speedup 1.0000x reference)
//
#include <hip/hip_runtime.h>
#include <cmath>

// Problem constants
#define NG    128       // graphs
#define NPER  512       // nodes per graph (layer 1)
#define NTOT  65536     // total nodes
#define NEDGE 1048576   // total edges
#define EPG   8192      // edges per graph
#define DIN   256
#define DD    128
#define K1    256       // kept nodes per graph after pool1
#define K2    128       // kept nodes per graph after pool2

// ---------------------------------------------------------------------------
// GEMM: C[M,128] = A[M,K] @ W[K,128]   (f32, LDS-tiled, 64 rows x 128 cols)
// ---------------------------------------------------------------------------
template<int K>
__global__ __launch_bounds__(256) void gemm_k(const float* __restrict__ A,
                                              const float* __restrict__ W,
                                              float* __restrict__ C) {
  __shared__ float As[64][64];
  __shared__ float Ws[64][128];
  const int tid = threadIdx.x;
  const int tx = tid & 31;       // col group (32 x float4 = 128 cols)
  const int ty = tid >> 5;       // row group (8 x 8 rows = 64 rows)
  const int c0 = tx * 4;
  const int r0 = ty * 8;
  const size_t row0 = (size_t)blockIdx.x * 64;

  float4 acc[8];
#pragma unroll
  for (int r = 0; r < 8; ++r) acc[r] = make_float4(0.f, 0.f, 0.f, 0.f);

  for (int kk = 0; kk < K; kk += 64) {
    // stage A tile 64x64
    {
      const int arow = tid >> 4;          // 0..15
      const int acol = (tid & 15) * 4;    // 0..60
#pragma unroll
      for (int i = 0; i < 4; ++i) {
        float4 v = *(const float4*)&A[(row0 + arow + i * 16) * K + kk + acol];
        *(float4*)&As[arow + i * 16][acol] = v;
      }
      const int wrow = tid >> 5;          // 0..7
      const int wcol = (tid & 31) * 4;    // 0..124
#pragma unroll
      for (int i = 0; i < 8; ++i) {
        *(float4*)&Ws[wrow + i * 8][wcol] =
            *(const float4*)&W[(size_t)(kk + wrow + i * 8) * 128 + wcol];
      }
    }
    __syncthreads();
#pragma unroll 8
    for (int k = 0; k < 64; ++k) {
      float4 wv = *(const float4*)&Ws[k][c0];
#pragma unroll
      for (int r = 0; r < 8; ++r) {
        float a = As[r0 + r][k];
        acc[r].x += a * wv.x; acc[r].y += a * wv.y;
        acc[r].z += a * wv.z; acc[r].w += a * wv.w;
      }
    }
    __syncthreads();
  }
#pragma unroll
  for (int r = 0; r < 8; ++r)
    *(float4*)&C[(row0 + r0 + r) * 128 + c0] = acc[r];
}

// ---------------------------------------------------------------------------
// Layer-1 aggregation: per (graph, 64-col chunk) block; LDS scatter-add.
// h = relu(agg + b_rel + xo)  (hout may alias xo)
// ---------------------------------------------------------------------------
__global__ __launch_bounds__(512) void agg1_kernel(
    const float* __restrict__ xr, const float* __restrict__ xo,
    const float* __restrict__ brel, const int* __restrict__ src,
    const int* __restrict__ dst, float* __restrict__ hout) {
  const int g = blockIdx.x >> 1;
  const int chunk = (blockIdx.x & 1) << 6;
  __shared__ float acc[NPER * 64];
  const int tid = threadIdx.x;
  for (int i = tid; i < NPER * 64; i += 512) acc[i] = 0.f;
  __syncthreads();
  const int lane = tid & 63, wave = tid >> 6;
  const int base = g * EPG + wave * 1024;
  for (int b = 0; b < 1024; b += 64) {
    int sv = src[base + b + lane];
    int dv = dst[base + b + lane];
#pragma unroll 8
    for (int i = 0; i < 64; ++i) {
      int s = __shfl(sv, i);
      int d = __shfl(dv, i);
      float val = xr[(size_t)s * 128 + chunk + lane];
      atomicAdd(&acc[(d - g * NPER) * 64 + lane], val);
    }
  }
  __syncthreads();
  const float bb = brel[chunk + lane];
  for (int n = wave; n < NPER; n += 8) {
    size_t gi = (size_t)(g * NPER + n) * 128 + chunk + lane;
    float v = acc[n * 64 + lane] + bb + xo[gi];
    hout[gi] = fmaxf(v, 0.f);
  }
}

// ---------------------------------------------------------------------------
// Layer-2 aggregation: same, with node relabel mapping and edge mask.
// ---------------------------------------------------------------------------
__global__ __launch_bounds__(512) void agg2_kernel(
    const float* __restrict__ xr, const float* __restrict__ xo,
    const float* __restrict__ brel, const int* __restrict__ src,
    const int* __restrict__ dst, const int* __restrict__ map,
    float* __restrict__ hout) {
  const int g = blockIdx.x >> 1;
  const int chunk = (blockIdx.x & 1) << 6;
  __shared__ float acc[K1 * 64];
  const int tid = threadIdx.x;
  for (int i = tid; i < K1 * 64; i += 512) acc[i] = 0.f;
  __syncthreads();
  const int lane = tid & 63, wave = tid >> 6;
  const int base = g * EPG + wave * 1024;
  for (int b = 0; b < 1024; b += 64) {
    int e = base + b + lane;
    int ms = map[src[e]];
    int md = map[dst[e]];
#pragma unroll 8
    for (int i = 0; i < 64; ++i) {
      int s = __shfl(ms, i);
      int d = __shfl(md, i);
      if ((s | d) >= 0) {   // both endpoints kept
        float val = xr[(size_t)s * 128 + chunk + lane];
        atomicAdd(&acc[(d - g * K1) * 64 + lane], val);
      }
    }
  }
  __syncthreads();
  const float bb = brel[chunk + lane];
  for (int n = wave; n < K1; n += 8) {
    size_t gi = (size_t)(g * K1 + n) * 128 + chunk + lane;
    float v = acc[n * 64 + lane] + bb + xo[gi];
    hout[gi] = fmaxf(v, 0.f);
  }
}

// ---------------------------------------------------------------------------
// TopK pool 1 (512 -> 256 per graph): scores, bitonic sort, x_new, mapping,
// score_1 output, global max/mean pools.
// ---------------------------------------------------------------------------
__global__ __launch_bounds__(512) void topk1_kernel(
    const float* __restrict__ h1, const float* __restrict__ pw,
    float* __restrict__ xnew, int* __restrict__ map,
    float* __restrict__ x1p, float* __restrict__ score_out) {
  const int g = blockIdx.x, tid = threadIdx.x;
  __shared__ float sc[NPER];
  __shared__ int si[NPER];
  __shared__ float xn[K1 * 128];
  __shared__ float wsh[128];
  __shared__ float redm[4 * 128];
  __shared__ float reds[4 * 128];
  if (tid < 128) wsh[tid] = pw[tid];
  __syncthreads();
  float nrm = 0.f;
  for (int i = 0; i < 128; ++i) nrm += wsh[i] * wsh[i];
  const float innorm = 1.f / sqrtf(nrm);

  // score per node
  {
    const float4* hp = (const float4*)&h1[(size_t)(g * NPER + tid) * 128];
    float s = 0.f;
#pragma unroll 8
    for (int j = 0; j < 32; ++j) {
      float4 v = hp[j];
      s += v.x * wsh[j * 4] + v.y * wsh[j * 4 + 1] +
           v.z * wsh[j * 4 + 2] + v.w * wsh[j * 4 + 3];
    }
    s *= innorm;
    s = 1.f / (1.f + expf(-s));
    sc[tid] = s;
    si[tid] = tid;
  }

  // bitonic sort, descending score, ties -> lower index first (lax.top_k)
  for (int k = 2; k <= NPER; k <<= 1) {
    for (int j = k >> 1; j > 0; j >>= 1) {
      __syncthreads();
      int p = tid ^ j;
      if (p > tid) {
        float sa = sc[tid], sb = sc[p];
        int ia = si[tid], ib = si[p];
        bool before = (sb > sa) || (sb == sa && ib < ia);
        if (before == ((tid & k) == 0)) {
          sc[tid] = sb; sc[p] = sa; si[tid] = ib; si[p] = ia;
        }
      }
    }
  }
  __syncthreads();

  map[g * NPER + tid] = -1;
  if (tid < K1) score_out[g * K1 + tid] = sc[tid];
  __syncthreads();
  if (tid < K1) map[g * NPER + si[tid]] = g * K1 + tid;

  const int wave = tid >> 6, lane = tid & 63;
  for (int j = wave; j < K1; j += 8) {
    int idx = si[j];
    float s2 = sc[j];
    float2 v = *(const float2*)&h1[(size_t)(g * NPER + idx) * 128 + lane * 2];
    float2 o;
    o.x = v.x * s2;
    o.y = v.y * s2;
    *(float2*)&xnew[(size_t)(g * K1 + j) * 128 + lane * 2] = o;
    xn[j * 128 + lane * 2] = o.x;
    xn[j * 128 + lane * 2 + 1] = o.y;
  }
  __syncthreads();

  // pools: max + mean over 256 rows
  const int c = tid & 127, grp = tid >> 7;   // 4 groups
  float mx = -1e30f, sm = 0.f;
  for (int r = grp; r < K1; r += 4) {
    float v = xn[r * 128 + c];
    mx = fmaxf(mx, v);
    sm += v;
  }
  redm[grp * 128 + c] = mx;
  reds[grp * 128 + c] = sm;
  __syncthreads();
  if (tid < 128) {
    float m = fmaxf(fmaxf(redm[c], redm[128 + c]), fmaxf(redm[256 + c], redm[384 + c]));
    float su = reds[c] + reds[128 + c] + reds[256 + c] + reds[384 + c];
    x1p[g * 256 + tid] = m;
    x1p[g * 256 + 128 + tid] = su * (1.f / 256.f);
  }
}

// ---------------------------------------------------------------------------
// TopK pool 2 (256 -> 128 per graph): pools only.
// ---------------------------------------------------------------------------
__global__ __launch_bounds__(256) void topk2_kernel(
    const float* __restrict__ h2, const float* __restrict__ pw,
    float* __restrict__ x2p) {
  const int g = blockIdx.x, tid = threadIdx.x;
  __shared__ float sc[K1];
  __shared__ int si[K1];
  __shared__ float xn[K2 * 128];
  __shared__ float wsh[128];
  __shared__ float redm[2 * 128];
  __shared__ float reds[2 * 128];
  if (tid < 128) wsh[tid] = pw[tid];
  __syncthreads();
  float nrm = 0.f;
  for (int i = 0; i < 128; ++i) nrm += wsh[i] * wsh[i];
  const float innorm = 1.f / sqrtf(nrm);
  {
    const float4* hp = (const float4*)&h2[(size_t)(g * K1 + tid) * 128];
    float s = 0.f;
#pragma unroll 8
    for (int j = 0; j < 32; ++j) {
      float4 v = hp[j];
      s += v.x * wsh[j * 4] + v.y * wsh[j * 4 + 1] +
           v.z * wsh[j * 4 + 2] + v.w * wsh[j * 4 + 3];
    }
    s *= innorm;
    s = 1.f / (1.f + expf(-s));
    sc[tid] = s;
    si[tid] = tid;
  }
  for (int k = 2; k <= K1; k <<= 1) {
    for (int j = k >> 1; j > 0; j >>= 1) {
      __syncthreads();
      int p = tid ^ j;
      if (p > tid) {
        float sa = sc[tid], sb = sc[p];
        int ia = si[tid], ib = si[p];
        bool before = (sb > sa) || (sb == sa && ib < ia);
        if (before == ((tid & k) == 0)) {
          sc[tid] = sb; sc[p] = sa; si[tid] = ib; si[p] = ia;
        }
      }
    }
  }
  __syncthreads();
  const int wave = tid >> 6, lane = tid & 63;  // 4 waves
  for (int j = wave; j < K2; j += 4) {
    int idx = si[j];
    float s2 = sc[j];
    float2 v = *(const float2*)&h2[(size_t)(g * K1 + idx) * 128 + lane * 2];
    xn[j * 128 + lane * 2] = v.x * s2;
    xn[j * 128 + lane * 2 + 1] = v.y * s2;
  }
  __syncthreads();
  const int c = tid & 127, grp = tid >> 7;  // 2 groups
  float mx = -1e30f, sm = 0.f;
  for (int r = grp; r < K2; r += 2) {
    float v = xn[r * 128 + c];
    mx = fmaxf(mx, v);
    sm += v;
  }
  redm[grp * 128 + c] = mx;
  reds[grp * 128 + c] = sm;
  __syncthreads();
  if (tid < 128) {
    float m = fmaxf(redm[c], redm[128 + c]);
    float su = reds[c] + reds[128 + c];
    x2p[g * 256 + tid] = m;
    x2p[g * 256 + 128 + tid] = su * (1.f / 128.f);
  }
}

// ---------------------------------------------------------------------------
// Head: g_emb = x1+x2; z = BN(relu(g_emb@lin1+b)); out = log_softmax(z@lin2+b)
// ---------------------------------------------------------------------------
__global__ __launch_bounds__(128) void head_kernel(
    const float* __restrict__ x1p, const float* __restrict__ x2p,
    const float* __restrict__ lin1_w, const float* __restrict__ lin1_b,
    const float* __restrict__ bng, const float* __restrict__ bnb,
    const float* __restrict__ bnm, const float* __restrict__ bnv,
    const float* __restrict__ lin2_w, const float* __restrict__ lin2_b,
    const float* __restrict__ pool1_w, float* __restrict__ out) {
  const int g = blockIdx.x, tid = threadIdx.x;
  __shared__ float ge[256];
  __shared__ float z[128];
  __shared__ float lg[16];
  for (int i = tid; i < 256; i += 128) {
    float v = x1p[g * 256 + i] + x2p[g * 256 + i];
    ge[i] = v;
    out[2048 + g * 256 + i] = v;   // g_emb output
  }
  __syncthreads();
  float a = lin1_b[tid];
  for (int k = 0; k < 256; ++k) a += ge[k] * lin1_w[k * 128 + tid];
  a = fmaxf(a, 0.f);
  a = (a - bnm[tid]) * bng[tid] / sqrtf(bnv[tid] + 1e-5f) + bnb[tid];
  z[tid] = a;
  __syncthreads();
  if (tid < 16) {
    float o = lin2_b[tid];
    for (int k = 0; k < 128; ++k) o += z[k] * lin2_w[k * 16 + tid];
    lg[tid] = o;
  }
  __syncthreads();
  if (tid < 16) {
    float m = lg[0];
    for (int j = 1; j < 16; ++j) m = fmaxf(m, lg[j]);
    float ssum = 0.f;
    for (int j = 0; j < 16; ++j) ssum += expf(lg[j] - m);
    out[g * 16 + tid] = lg[tid] - m - logf(ssum);
  }
  if (g == 0 && tid < 128) out[34816 + tid] = pool1_w[tid];  // pool1_w output
}

// ---------------------------------------------------------------------------
extern "C" void kernel_launch(void* const* d_in, const int* in_sizes, int n_in,
                              void* d_out, int out_size, void* d_ws, size_t ws_size,
                              hipStream_t stream) {
  const float* x       = (const float*)d_in[0];
  const int*   ei      = (const int*)d_in[1];
  const float* w_rel1  = (const float*)d_in[3];
  const float* b_rel1  = (const float*)d_in[4];
  const float* w_root1 = (const float*)d_in[5];
  const float* pool1_w = (const float*)d_in[6];
  const float* w_rel2  = (const float*)d_in[7];
  const float* b_rel2  = (const float*)d_in[8];
  const float* w_root2 = (const float*)d_in[9];
  const float* pool2_w = (const float*)d_in[10];
  const float* lin1_w  = (const float*)d_in[11];
  const float* lin1_b  = (const float*)d_in[12];
  const float* bng     = (const float*)d_in[13];
  const float* bnb     = (const float*)d_in[14];
  const float* bnm     = (const float*)d_in[15];
  const float* bnv     = (const float*)d_in[16];
  const float* lin2_w  = (const float*)d_in[17];
  const float* lin2_b  = (const float*)d_in[18];
  const int* src = ei;
  const int* dst = ei + NEDGE;

  char* ws = (char*)d_ws;
  float* xr1  = (float*)(ws + 0);              // 32 MB  [N,128]
  float* xoh1 = (float*)(ws + 33554432UL);     // 32 MB  xo1 then h1 (in place)
  float* xnew = (float*)(ws + 67108864UL);     // 16 MB  [G*K1,128]
  int*   map  = (int*)  (ws + 83886080UL);     // 256 KB [N]
  float* x1p  = (float*)(ws + 84148224UL);     // 128 KB [G,256]
  float* x2p  = (float*)(ws + 84279296UL);     // 128 KB [G,256]
  float* xr2  = (float*)(ws + 0);              // reuse xr1 region (16 MB)
  float* xo2  = (float*)(ws + 16777216UL);     // upper half of xr1 region
  float* h2   = xoh1;                          // reuse (16 MB)
  float* out  = (float*)d_out;

  // Layer 1
  gemm_k<256><<<dim3(1024), dim3(256), 0, stream>>>(x, w_rel1, xr1);
  gemm_k<256><<<dim3(1024), dim3(256), 0, stream>>>(x, w_root1, xoh1);
  agg1_kernel<<<dim3(256), dim3(512), 0, stream>>>(xr1, xoh1, b_rel1, src, dst, xoh1);
  topk1_kernel<<<dim3(128), dim3(512), 0, stream>>>(xoh1, pool1_w, xnew, map, x1p, out + 34944);

  // Layer 2
  gemm_k<128><<<dim3(512), dim3(256), 0, stream>>>(xnew, w_rel2, xr2);
  gemm_k<128><<<dim3(512), dim3(256), 0, stream>>>(xnew, w_root2, xo2);
  agg2_kernel<<<dim3(256), dim3(512), 0, stream>>>(xr2, xo2, b_rel2, src, dst, map, h2);
  topk2_kernel<<<dim3(128), dim3(256), 0, stream>>>(h2, pool2_w, x2p);

  // Head
  head_kernel<<<dim3(128), dim3(128), 0, stream>>>(x1p, x2p, lin1_w, lin1_b,
      bng, bnb, bnm, bnv, lin2_w, lin2_b, pool1_w, out);
}

// Round 2
// 349.019 us; speedup vs baseline: 3.3030x; 3.3030x over previous
//
#include <hip/hip_runtime.h>
#include <cmath>

// Problem constants
#define NG    128       // graphs
#define NPER  512       // nodes per graph (layer 1)
#define NTOT  65536     // total nodes
#define NEDGE 1048576   // total edges
#define EPG   8192      // edges per graph
#define DIN   256
#define DD    128
#define K1    256       // kept nodes per graph after pool1
#define K2    128       // kept nodes per graph after pool2

// ---------------------------------------------------------------------------
// Dual GEMM: C1 = A@W1, C2 = A@W2   [M,K]x[K,128] f32, 64-row x 128-col tiles
// ---------------------------------------------------------------------------
template<int K>
__global__ __launch_bounds__(256) void gemm_dual(const float* __restrict__ A,
                                                 const float* __restrict__ W1,
                                                 const float* __restrict__ W2,
                                                 float* __restrict__ C1,
                                                 float* __restrict__ C2) {
  __shared__ float As[64][64];
  __shared__ float Ws1[64][128];
  __shared__ float Ws2[64][128];
  const int tid = threadIdx.x;
  const int tx = tid & 31;       // col group (32 x float4 = 128 cols)
  const int ty = tid >> 5;       // row group (8 x 8 rows = 64 rows)
  const int c0 = tx * 4;
  const int r0 = ty * 8;
  const size_t row0 = (size_t)blockIdx.x * 64;

  float4 acc1[8], acc2[8];
#pragma unroll
  for (int r = 0; r < 8; ++r) {
    acc1[r] = make_float4(0.f, 0.f, 0.f, 0.f);
    acc2[r] = make_float4(0.f, 0.f, 0.f, 0.f);
  }

  for (int kk = 0; kk < K; kk += 64) {
    {
      const int arow = tid >> 4;          // 0..15
      const int acol = (tid & 15) * 4;    // 0..60
#pragma unroll
      for (int i = 0; i < 4; ++i) {
        float4 v = *(const float4*)&A[(row0 + arow + i * 16) * K + kk + acol];
        *(float4*)&As[arow + i * 16][acol] = v;
      }
      const int wrow = tid >> 5;          // 0..7
      const int wcol = (tid & 31) * 4;    // 0..124
#pragma unroll
      for (int i = 0; i < 8; ++i) {
        *(float4*)&Ws1[wrow + i * 8][wcol] =
            *(const float4*)&W1[(size_t)(kk + wrow + i * 8) * 128 + wcol];
        *(float4*)&Ws2[wrow + i * 8][wcol] =
            *(const float4*)&W2[(size_t)(kk + wrow + i * 8) * 128 + wcol];
      }
    }
    __syncthreads();
#pragma unroll 8
    for (int k = 0; k < 64; ++k) {
      float4 w1 = *(const float4*)&Ws1[k][c0];
      float4 w2 = *(const float4*)&Ws2[k][c0];
#pragma unroll
      for (int r = 0; r < 8; ++r) {
        float a = As[r0 + r][k];
        acc1[r].x += a * w1.x; acc1[r].y += a * w1.y;
        acc1[r].z += a * w1.z; acc1[r].w += a * w1.w;
        acc2[r].x += a * w2.x; acc2[r].y += a * w2.y;
        acc2[r].z += a * w2.z; acc2[r].w += a * w2.w;
      }
    }
    __syncthreads();
  }
#pragma unroll
  for (int r = 0; r < 8; ++r) {
    *(float4*)&C1[(row0 + r0 + r) * 128 + c0] = acc1[r];
    *(float4*)&C2[(row0 + r0 + r) * 128 + c0] = acc2[r];
  }
}

// ---------------------------------------------------------------------------
// CSR build
// ---------------------------------------------------------------------------
__global__ __launch_bounds__(512) void csr_count1(const int* __restrict__ dst,
                                                  int* __restrict__ deg) {
  int e = blockIdx.x * 512 + threadIdx.x;
  atomicAdd(&deg[dst[e]], 1);
}

__global__ __launch_bounds__(512) void csr_fill1(const int* __restrict__ src,
                                                 const int* __restrict__ dst,
                                                 int* __restrict__ cursor,
                                                 int* __restrict__ eid) {
  int e = blockIdx.x * 512 + threadIdx.x;
  int pos = atomicAdd(&cursor[dst[e]], 1);
  eid[pos] = src[e];
}

__global__ __launch_bounds__(512) void csr_count2(const int* __restrict__ src,
                                                  const int* __restrict__ dst,
                                                  const int* __restrict__ map,
                                                  int* __restrict__ deg) {
  int e = blockIdx.x * 512 + threadIdx.x;
  int ms = map[src[e]], md = map[dst[e]];
  if ((ms | md) >= 0) atomicAdd(&deg[md], 1);
}

__global__ __launch_bounds__(512) void csr_fill2(const int* __restrict__ src,
                                                 const int* __restrict__ dst,
                                                 const int* __restrict__ map,
                                                 int* __restrict__ cursor,
                                                 int* __restrict__ eid) {
  int e = blockIdx.x * 512 + threadIdx.x;
  int ms = map[src[e]], md = map[dst[e]];
  if ((ms | md) >= 0) {
    int pos = atomicAdd(&cursor[md], 1);
    eid[pos] = ms;
  }
}

// Exclusive scan of degrees within each graph (block = NPG threads).
template<int NPG>
__global__ void csr_scan(const int* __restrict__ deg, int* __restrict__ rowptr,
                         int* __restrict__ cursor) {
  __shared__ int buf[NPG];
  const int g = blockIdx.x, tid = threadIdx.x;
  int d = deg[g * NPG + tid];
  buf[tid] = d;
  __syncthreads();
  for (int off = 1; off < NPG; off <<= 1) {
    int v = (tid >= off) ? buf[tid - off] : 0;
    __syncthreads();
    buf[tid] += v;
    __syncthreads();
  }
  int rp = g * EPG + buf[tid] - d;
  rowptr[g * NPG + tid] = rp;
  cursor[g * NPG + tid] = rp;
}

// ---------------------------------------------------------------------------
// Gather aggregation: one wave per node. h = relu(sum_nb xr[nb] + b + xo)
// hout may alias xo.
// ---------------------------------------------------------------------------
__global__ __launch_bounds__(512) void agg_gather(
    const float* __restrict__ xr, const float* __restrict__ xo,
    const float* __restrict__ brel, const int* __restrict__ rowptr,
    const int* __restrict__ deg, const int* __restrict__ eid,
    float* __restrict__ hout, int nnodes) {
  const int wave = threadIdx.x >> 6, lane = threadIdx.x & 63;
  const int node = blockIdx.x * 8 + wave;
  if (node >= nnodes) return;
  const int start = rowptr[node];
  const int dg = deg[node];
  float2 a0 = {0.f, 0.f}, a1 = {0.f, 0.f}, a2 = {0.f, 0.f}, a3 = {0.f, 0.f};
  int j = 0;
  for (; j + 4 <= dg; j += 4) {
    int n0 = eid[start + j + 0];
    int n1 = eid[start + j + 1];
    int n2 = eid[start + j + 2];
    int n3 = eid[start + j + 3];
    float2 v0 = *(const float2*)&xr[(size_t)n0 * 128 + lane * 2];
    float2 v1 = *(const float2*)&xr[(size_t)n1 * 128 + lane * 2];
    float2 v2 = *(const float2*)&xr[(size_t)n2 * 128 + lane * 2];
    float2 v3 = *(const float2*)&xr[(size_t)n3 * 128 + lane * 2];
    a0.x += v0.x; a0.y += v0.y;
    a1.x += v1.x; a1.y += v1.y;
    a2.x += v2.x; a2.y += v2.y;
    a3.x += v3.x; a3.y += v3.y;
  }
  for (; j < dg; ++j) {
    int n0 = eid[start + j];
    float2 v0 = *(const float2*)&xr[(size_t)n0 * 128 + lane * 2];
    a0.x += v0.x; a0.y += v0.y;
  }
  float2 b = *(const float2*)&brel[lane * 2];
  float2 o = *(const float2*)&xo[(size_t)node * 128 + lane * 2];
  float2 h;
  h.x = fmaxf(a0.x + a1.x + a2.x + a3.x + b.x + o.x, 0.f);
  h.y = fmaxf(a0.y + a1.y + a2.y + a3.y + b.y + o.y, 0.f);
  *(float2*)&hout[(size_t)node * 128 + lane * 2] = h;
}

// ---------------------------------------------------------------------------
// TopK pool 1 (512 -> 256 per graph)
// ---------------------------------------------------------------------------
__global__ __launch_bounds__(512) void topk1_kernel(
    const float* __restrict__ h1, const float* __restrict__ pw,
    float* __restrict__ xnew, int* __restrict__ map,
    float* __restrict__ x1p, float* __restrict__ score_out) {
  const int g = blockIdx.x, tid = threadIdx.x;
  __shared__ float sc[NPER];
  __shared__ int si[NPER];
  __shared__ float xn[K1 * 128];
  __shared__ float wsh[128];
  __shared__ float redm[4 * 128];
  __shared__ float reds[4 * 128];
  if (tid < 128) wsh[tid] = pw[tid];
  __syncthreads();
  float nrm = 0.f;
  for (int i = 0; i < 128; ++i) nrm += wsh[i] * wsh[i];
  const float innorm = 1.f / sqrtf(nrm);

  {
    const float4* hp = (const float4*)&h1[(size_t)(g * NPER + tid) * 128];
    float s = 0.f;
#pragma unroll 8
    for (int j = 0; j < 32; ++j) {
      float4 v = hp[j];
      s += v.x * wsh[j * 4] + v.y * wsh[j * 4 + 1] +
           v.z * wsh[j * 4 + 2] + v.w * wsh[j * 4 + 3];
    }
    s *= innorm;
    s = 1.f / (1.f + expf(-s));
    sc[tid] = s;
    si[tid] = tid;
  }

  // bitonic sort, descending score, ties -> lower index first (lax.top_k)
  for (int k = 2; k <= NPER; k <<= 1) {
    for (int j = k >> 1; j > 0; j >>= 1) {
      __syncthreads();
      int p = tid ^ j;
      if (p > tid) {
        float sa = sc[tid], sb = sc[p];
        int ia = si[tid], ib = si[p];
        bool before = (sb > sa) || (sb == sa && ib < ia);
        if (before == ((tid & k) == 0)) {
          sc[tid] = sb; sc[p] = sa; si[tid] = ib; si[p] = ia;
        }
      }
    }
  }
  __syncthreads();

  map[g * NPER + tid] = -1;
  if (tid < K1) score_out[g * K1 + tid] = sc[tid];
  __syncthreads();
  if (tid < K1) map[g * NPER + si[tid]] = g * K1 + tid;

  const int wave = tid >> 6, lane = tid & 63;
  for (int j = wave; j < K1; j += 8) {
    int idx = si[j];
    float s2 = sc[j];
    float2 v = *(const float2*)&h1[(size_t)(g * NPER + idx) * 128 + lane * 2];
    float2 o;
    o.x = v.x * s2;
    o.y = v.y * s2;
    *(float2*)&xnew[(size_t)(g * K1 + j) * 128 + lane * 2] = o;
    xn[j * 128 + lane * 2] = o.x;
    xn[j * 128 + lane * 2 + 1] = o.y;
  }
  __syncthreads();

  const int c = tid & 127, grp = tid >> 7;   // 4 groups
  float mx = -1e30f, sm = 0.f;
  for (int r = grp; r < K1; r += 4) {
    float v = xn[r * 128 + c];
    mx = fmaxf(mx, v);
    sm += v;
  }
  redm[grp * 128 + c] = mx;
  reds[grp * 128 + c] = sm;
  __syncthreads();
  if (tid < 128) {
    float m = fmaxf(fmaxf(redm[c], redm[128 + c]), fmaxf(redm[256 + c], redm[384 + c]));
    float su = reds[c] + reds[128 + c] + reds[256 + c] + reds[384 + c];
    x1p[g * 256 + tid] = m;
    x1p[g * 256 + 128 + tid] = su * (1.f / 256.f);
  }
}

// ---------------------------------------------------------------------------
// TopK pool 2 (256 -> 128 per graph): pools only.
// ---------------------------------------------------------------------------
__global__ __launch_bounds__(256) void topk2_kernel(
    const float* __restrict__ h2, const float* __restrict__ pw,
    float* __restrict__ x2p) {
  const int g = blockIdx.x, tid = threadIdx.x;
  __shared__ float sc[K1];
  __shared__ int si[K1];
  __shared__ float xn[K2 * 128];
  __shared__ float wsh[128];
  __shared__ float redm[2 * 128];
  __shared__ float reds[2 * 128];
  if (tid < 128) wsh[tid] = pw[tid];
  __syncthreads();
  float nrm = 0.f;
  for (int i = 0; i < 128; ++i) nrm += wsh[i] * wsh[i];
  const float innorm = 1.f / sqrtf(nrm);
  {
    const float4* hp = (const float4*)&h2[(size_t)(g * K1 + tid) * 128];
    float s = 0.f;
#pragma unroll 8
    for (int j = 0; j < 32; ++j) {
      float4 v = hp[j];
      s += v.x * wsh[j * 4] + v.y * wsh[j * 4 + 1] +
           v.z * wsh[j * 4 + 2] + v.w * wsh[j * 4 + 3];
    }
    s *= innorm;
    s = 1.f / (1.f + expf(-s));
    sc[tid] = s;
    si[tid] = tid;
  }
  for (int k = 2; k <= K1; k <<= 1) {
    for (int j = k >> 1; j > 0; j >>= 1) {
      __syncthreads();
      int p = tid ^ j;
      if (p > tid) {
        float sa = sc[tid], sb = sc[p];
        int ia = si[tid], ib = si[p];
        bool before = (sb > sa) || (sb == sa && ib < ia);
        if (before == ((tid & k) == 0)) {
          sc[tid] = sb; sc[p] = sa; si[tid] = ib; si[p] = ia;
        }
      }
    }
  }
  __syncthreads();
  const int wave = tid >> 6, lane = tid & 63;  // 4 waves
  for (int j = wave; j < K2; j += 4) {
    int idx = si[j];
    float s2 = sc[j];
    float2 v = *(const float2*)&h2[(size_t)(g * K1 + idx) * 128 + lane * 2];
    xn[j * 128 + lane * 2] = v.x * s2;
    xn[j * 128 + lane * 2 + 1] = v.y * s2;
  }
  __syncthreads();
  const int c = tid & 127, grp = tid >> 7;  // 2 groups
  float mx = -1e30f, sm = 0.f;
  for (int r = grp; r < K2; r += 2) {
    float v = xn[r * 128 + c];
    mx = fmaxf(mx, v);
    sm += v;
  }
  redm[grp * 128 + c] = mx;
  reds[grp * 128 + c] = sm;
  __syncthreads();
  if (tid < 128) {
    float m = fmaxf(redm[c], redm[128 + c]);
    float su = reds[c] + reds[128 + c];
    x2p[g * 256 + tid] = m;
    x2p[g * 256 + 128 + tid] = su * (1.f / 128.f);
  }
}

// ---------------------------------------------------------------------------
// Head
// ---------------------------------------------------------------------------
__global__ __launch_bounds__(128) void head_kernel(
    const float* __restrict__ x1p, const float* __restrict__ x2p,
    const float* __restrict__ lin1_w, const float* __restrict__ lin1_b,
    const float* __restrict__ bng, const float* __restrict__ bnb,
    const float* __restrict__ bnm, const float* __restrict__ bnv,
    const float* __restrict__ lin2_w, const float* __restrict__ lin2_b,
    const float* __restrict__ pool1_w, float* __restrict__ out) {
  const int g = blockIdx.x, tid = threadIdx.x;
  __shared__ float ge[256];
  __shared__ float z[128];
  __shared__ float lg[16];
  for (int i = tid; i < 256; i += 128) {
    float v = x1p[g * 256 + i] + x2p[g * 256 + i];
    ge[i] = v;
    out[2048 + g * 256 + i] = v;   // g_emb output
  }
  __syncthreads();
  float a = lin1_b[tid];
  for (int k = 0; k < 256; ++k) a += ge[k] * lin1_w[k * 128 + tid];
  a = fmaxf(a, 0.f);
  a = (a - bnm[tid]) * bng[tid] / sqrtf(bnv[tid] + 1e-5f) + bnb[tid];
  z[tid] = a;
  __syncthreads();
  if (tid < 16) {
    float o = lin2_b[tid];
    for (int k = 0; k < 128; ++k) o += z[k] * lin2_w[k * 16 + tid];
    lg[tid] = o;
  }
  __syncthreads();
  if (tid < 16) {
    float m = lg[0];
    for (int j = 1; j < 16; ++j) m = fmaxf(m, lg[j]);
    float ssum = 0.f;
    for (int j = 0; j < 16; ++j) ssum += expf(lg[j] - m);
    out[g * 16 + tid] = lg[tid] - m - logf(ssum);
  }
  if (g == 0 && tid < 128) out[34816 + tid] = pool1_w[tid];  // pool1_w output
}

// ---------------------------------------------------------------------------
extern "C" void kernel_launch(void* const* d_in, const int* in_sizes, int n_in,
                              void* d_out, int out_size, void* d_ws, size_t ws_size,
                              hipStream_t stream) {
  const float* x       = (const float*)d_in[0];
  const int*   ei      = (const int*)d_in[1];
  const float* w_rel1  = (const float*)d_in[3];
  const float* b_rel1  = (const float*)d_in[4];
  const float* w_root1 = (const float*)d_in[5];
  const float* pool1_w = (const float*)d_in[6];
  const float* w_rel2  = (const float*)d_in[7];
  const float* b_rel2  = (const float*)d_in[8];
  const float* w_root2 = (const float*)d_in[9];
  const float* pool2_w = (const float*)d_in[10];
  const float* lin1_w  = (const float*)d_in[11];
  const float* lin1_b  = (const float*)d_in[12];
  const float* bng     = (const float*)d_in[13];
  const float* bnb     = (const float*)d_in[14];
  const float* bnm     = (const float*)d_in[15];
  const float* bnv     = (const float*)d_in[16];
  const float* lin2_w  = (const float*)d_in[17];
  const float* lin2_b  = (const float*)d_in[18];
  const int* src = ei;
  const int* dst = ei + NEDGE;

  char* ws = (char*)d_ws;
  // Layout (bytes):
  //   [0, 32M)      xr1 [N,128]        ; layer2: xr2 [32768,128] + xo2
  //   [32M, 64M)    xo1/h1 in place    ; layer2: h2 (first 16M)
  //   [64M, 80M)    eid1 (4M, dead after agg1) then xnew [32768,128]
  //                 then eid2 (4M, after gemm_dual2 consumed xnew)
  //   [80M, ...)    map, rowptr, cursor, deg, x1p, x2p
  float* xr1  = (float*)(ws + 0);
  float* xoh1 = (float*)(ws + 33554432UL);
  float* xnew = (float*)(ws + 67108864UL);
  int*   eid  = (int*)  (ws + 67108864UL);
  int*   map  = (int*)  (ws + 83886080UL);
  int*   rowptr = (int*)(ws + 84148224UL);
  int*   cursor = (int*)(ws + 84410368UL);
  int*   deg  = (int*)  (ws + 84672512UL);
  float* x1p  = (float*)(ws + 84934656UL);
  float* x2p  = (float*)(ws + 85065728UL);
  float* xr2  = (float*)(ws + 0);
  float* xo2  = (float*)(ws + 16777216UL);
  float* h2   = xoh1;
  float* out  = (float*)d_out;

  // ---- Layer 1 ----
  gemm_dual<256><<<dim3(1024), dim3(256), 0, stream>>>(x, w_rel1, w_root1, xr1, xoh1);
  hipMemsetAsync(deg, 0, NTOT * sizeof(int), stream);
  csr_count1<<<dim3(NEDGE / 512), dim3(512), 0, stream>>>(dst, deg);
  csr_scan<NPER><<<dim3(NG), dim3(NPER), 0, stream>>>(deg, rowptr, cursor);
  csr_fill1<<<dim3(NEDGE / 512), dim3(512), 0, stream>>>(src, dst, cursor, eid);
  agg_gather<<<dim3(NTOT / 8), dim3(512), 0, stream>>>(
      xr1, xoh1, b_rel1, rowptr, deg, eid, xoh1, NTOT);
  topk1_kernel<<<dim3(NG), dim3(512), 0, stream>>>(xoh1, pool1_w, xnew, map, x1p, out + 34944);

  // ---- Layer 2 ----
  gemm_dual<128><<<dim3(512), dim3(256), 0, stream>>>(xnew, w_rel2, w_root2, xr2, xo2);
  hipMemsetAsync(deg, 0, NG * K1 * sizeof(int), stream);
  csr_count2<<<dim3(NEDGE / 512), dim3(512), 0, stream>>>(src, dst, map, deg);
  csr_scan<K1><<<dim3(NG), dim3(K1), 0, stream>>>(deg, rowptr, cursor);
  csr_fill2<<<dim3(NEDGE / 512), dim3(512), 0, stream>>>(src, dst, map, cursor, eid);
  agg_gather<<<dim3(NG * K1 / 8), dim3(512), 0, stream>>>(
      xr2, xo2, b_rel2, rowptr, deg, eid, h2, NG * K1);
  topk2_kernel<<<dim3(NG), dim3(K1), 0, stream>>>(h2, pool2_w, x2p);

  // ---- Head ----
  head_kernel<<<dim3(NG), dim3(128), 0, stream>>>(x1p, x2p, lin1_w, lin1_b,
      bng, bnb, bnm, bnv, lin2_w, lin2_b, pool1_w, out);
}

// Round 3
// 296.423 us; speedup vs baseline: 3.8890x; 1.1774x over previous
//
#include <hip/hip_runtime.h>
#include <cmath>

// Problem constants
#define NG    128       // graphs
#define NPER  512       // nodes per graph (layer 1)
#define NTOT  65536     // total nodes
#define NEDGE 1048576   // total edges
#define EPG   8192      // edges per graph
#define DIN   256
#define DD    128
#define K1    256       // kept nodes per graph after pool1
#define K2    128       // kept nodes per graph after pool2

typedef float f32x4 __attribute__((ext_vector_type(4)));
typedef short short8 __attribute__((ext_vector_type(8)));

// ---------------------------------------------------------------------------
// Prep: wt[n][k] (n 0..255 = cols of W1 then W2), split into bf16 hi/lo.
// W1,W2 are [K][128] row-major. Truncation split: a = hi + lo + O(2^-14 a).
// ---------------------------------------------------------------------------
__global__ void build_wt(const float* __restrict__ W1, const float* __restrict__ W2,
                         short* __restrict__ wth, short* __restrict__ wtl, int K) {
  const int n = blockIdx.x, k = threadIdx.x;
  float w = (n < 128) ? W1[k * 128 + n] : W2[k * 128 + (n - 128)];
  unsigned u = __builtin_bit_cast(unsigned, w);
  wth[n * K + k] = (short)(u >> 16);
  float lf = w - __builtin_bit_cast(float, u & 0xFFFF0000u);
  wtl[n * K + k] = (short)(__builtin_bit_cast(unsigned, lf) >> 16);
}

// ---------------------------------------------------------------------------
// Split-bf16 MFMA dual GEMM: C1 = A@W1, C2 = A@W2 (f32-accurate via 3 terms)
// A [M,K] f32; wt = [256][K] bf16 hi/lo (cols of W1|W2, k-contiguous).
// Tile: 128M x 256N, BK=32. 4 waves (2x2), per-wave 64Mx128N (4x8 frags).
// ---------------------------------------------------------------------------
template<int K>
__global__ __launch_bounds__(256) void gemm_mfma_dual(
    const float* __restrict__ A,
    const short* __restrict__ wth, const short* __restrict__ wtl,
    float* __restrict__ C1, float* __restrict__ C2) {
  // rows padded to 40 shorts (80 B): 16B-aligned b128 reads, 2-way banks (free)
  __shared__ short Ah[128][40], Al[128][40];
  __shared__ short Wh[256][40], Wl[256][40];
  const int tid = threadIdx.x;
  const int lane = tid & 63;
  const int wid = tid >> 6;
  const int wm = (wid >> 1) * 64;     // wave m-offset
  const int wn = (wid & 1) * 128;     // wave n-offset (0 -> C1, 128 -> C2)
  const size_t row0 = (size_t)blockIdx.x * 128;
  const int l15 = lane & 15, kq = (lane >> 4) * 8;
  const int ar = tid >> 1, ac = (tid & 1) * 16;   // A staging: row, col half

  f32x4 acc[4][8];
#pragma unroll
  for (int mf = 0; mf < 4; ++mf)
#pragma unroll
    for (int nf = 0; nf < 8; ++nf) acc[mf][nf] = (f32x4){0.f, 0.f, 0.f, 0.f};

  for (int kk = 0; kk < K; kk += 32) {
    // ---- stage A tile (f32 -> bf16 hi/lo) ----
    {
      const float* ap = A + (row0 + ar) * K + kk + ac;
      float4 v0 = ((const float4*)ap)[0];
      float4 v1 = ((const float4*)ap)[1];
      float4 v2 = ((const float4*)ap)[2];
      float4 v3 = ((const float4*)ap)[3];
      float vv[16] = {v0.x, v0.y, v0.z, v0.w, v1.x, v1.y, v1.z, v1.w,
                      v2.x, v2.y, v2.z, v2.w, v3.x, v3.y, v3.z, v3.w};
      short hb[16], lb[16];
#pragma unroll
      for (int i = 0; i < 16; ++i) {
        unsigned u = __builtin_bit_cast(unsigned, vv[i]);
        hb[i] = (short)(u >> 16);
        float lf = vv[i] - __builtin_bit_cast(float, u & 0xFFFF0000u);
        lb[i] = (short)(__builtin_bit_cast(unsigned, lf) >> 16);
      }
      *(short8*)&Ah[ar][ac]     = *(short8*)&hb[0];
      *(short8*)&Ah[ar][ac + 8] = *(short8*)&hb[8];
      *(short8*)&Al[ar][ac]     = *(short8*)&lb[0];
      *(short8*)&Al[ar][ac + 8] = *(short8*)&lb[8];
    }
    // ---- stage W tile (pre-split, k-contiguous; L2-resident) ----
    {
      const short* wr = wth + (size_t)tid * K + kk;
      const short* wl = wtl + (size_t)tid * K + kk;
#pragma unroll
      for (int i = 0; i < 4; ++i) {
        *(int4*)&Wh[tid][i * 8] = ((const int4*)wr)[i];
        *(int4*)&Wl[tid][i * 8] = ((const int4*)wl)[i];
      }
    }
    __syncthreads();

    short8 bh[8], bl[8];
#pragma unroll
    for (int nf = 0; nf < 8; ++nf) {
      int rn = wn + nf * 16 + l15;
      bh[nf] = *(const short8*)&Wh[rn][kq];
      bl[nf] = *(const short8*)&Wl[rn][kq];
    }
#pragma unroll
    for (int mf = 0; mf < 4; ++mf) {
      int rm = wm + mf * 16 + l15;
      short8 ahf = *(const short8*)&Ah[rm][kq];
      short8 alf = *(const short8*)&Al[rm][kq];
#pragma unroll
      for (int nf = 0; nf < 8; ++nf) {
        acc[mf][nf] = __builtin_amdgcn_mfma_f32_16x16x32_bf16(ahf, bh[nf], acc[mf][nf], 0, 0, 0);
        acc[mf][nf] = __builtin_amdgcn_mfma_f32_16x16x32_bf16(ahf, bl[nf], acc[mf][nf], 0, 0, 0);
        acc[mf][nf] = __builtin_amdgcn_mfma_f32_16x16x32_bf16(alf, bh[nf], acc[mf][nf], 0, 0, 0);
      }
    }
    __syncthreads();
  }

  // epilogue: D lane mapping col=lane&15, row=(lane>>4)*4+r
  float* Cb = (wn == 0) ? C1 : C2;
#pragma unroll
  for (int mf = 0; mf < 4; ++mf) {
    size_t rbase = row0 + wm + mf * 16 + (lane >> 4) * 4;
#pragma unroll
    for (int nf = 0; nf < 8; ++nf) {
      int c = nf * 16 + l15;
#pragma unroll
      for (int r = 0; r < 4; ++r)
        Cb[(rbase + r) * 128 + c] = acc[mf][nf][r];
    }
  }
}

// ---------------------------------------------------------------------------
// CSR build
// ---------------------------------------------------------------------------
__global__ __launch_bounds__(512) void csr_count1(const int* __restrict__ dst,
                                                  int* __restrict__ deg) {
  int e = blockIdx.x * 512 + threadIdx.x;
  atomicAdd(&deg[dst[e]], 1);
}

__global__ __launch_bounds__(512) void csr_fill1(const int* __restrict__ src,
                                                 const int* __restrict__ dst,
                                                 int* __restrict__ cursor,
                                                 int* __restrict__ eid) {
  int e = blockIdx.x * 512 + threadIdx.x;
  int pos = atomicAdd(&cursor[dst[e]], 1);
  eid[pos] = src[e];
}

__global__ __launch_bounds__(512) void csr_count2(const int* __restrict__ src,
                                                  const int* __restrict__ dst,
                                                  const int* __restrict__ map,
                                                  int* __restrict__ deg) {
  int e = blockIdx.x * 512 + threadIdx.x;
  int ms = map[src[e]], md = map[dst[e]];
  if ((ms | md) >= 0) atomicAdd(&deg[md], 1);
}

__global__ __launch_bounds__(512) void csr_fill2(const int* __restrict__ src,
                                                 const int* __restrict__ dst,
                                                 const int* __restrict__ map,
                                                 int* __restrict__ cursor,
                                                 int* __restrict__ eid) {
  int e = blockIdx.x * 512 + threadIdx.x;
  int ms = map[src[e]], md = map[dst[e]];
  if ((ms | md) >= 0) {
    int pos = atomicAdd(&cursor[md], 1);
    eid[pos] = ms;
  }
}

// Exclusive scan of degrees within each graph (block = NPG threads).
template<int NPG>
__global__ void csr_scan(const int* __restrict__ deg, int* __restrict__ rowptr,
                         int* __restrict__ cursor) {
  __shared__ int buf[NPG];
  const int g = blockIdx.x, tid = threadIdx.x;
  int d = deg[g * NPG + tid];
  buf[tid] = d;
  __syncthreads();
  for (int off = 1; off < NPG; off <<= 1) {
    int v = (tid >= off) ? buf[tid - off] : 0;
    __syncthreads();
    buf[tid] += v;
    __syncthreads();
  }
  int rp = g * EPG + buf[tid] - d;
  rowptr[g * NPG + tid] = rp;
  cursor[g * NPG + tid] = rp;
}

// ---------------------------------------------------------------------------
// Gather aggregation: one wave per node. h = relu(sum_nb xr[nb] + b + xo)
// ---------------------------------------------------------------------------
__global__ __launch_bounds__(512) void agg_gather(
    const float* __restrict__ xr, const float* __restrict__ xo,
    const float* __restrict__ brel, const int* __restrict__ rowptr,
    const int* __restrict__ deg, const int* __restrict__ eid,
    float* __restrict__ hout, int nnodes) {
  const int wave = threadIdx.x >> 6, lane = threadIdx.x & 63;
  const int node = blockIdx.x * 8 + wave;
  if (node >= nnodes) return;
  const int start = rowptr[node];
  const int dg = deg[node];
  float2 a0 = {0.f, 0.f}, a1 = {0.f, 0.f}, a2 = {0.f, 0.f}, a3 = {0.f, 0.f};
  int j = 0;
  for (; j + 4 <= dg; j += 4) {
    int n0 = eid[start + j + 0];
    int n1 = eid[start + j + 1];
    int n2 = eid[start + j + 2];
    int n3 = eid[start + j + 3];
    float2 v0 = *(const float2*)&xr[(size_t)n0 * 128 + lane * 2];
    float2 v1 = *(const float2*)&xr[(size_t)n1 * 128 + lane * 2];
    float2 v2 = *(const float2*)&xr[(size_t)n2 * 128 + lane * 2];
    float2 v3 = *(const float2*)&xr[(size_t)n3 * 128 + lane * 2];
    a0.x += v0.x; a0.y += v0.y;
    a1.x += v1.x; a1.y += v1.y;
    a2.x += v2.x; a2.y += v2.y;
    a3.x += v3.x; a3.y += v3.y;
  }
  for (; j < dg; ++j) {
    int n0 = eid[start + j];
    float2 v0 = *(const float2*)&xr[(size_t)n0 * 128 + lane * 2];
    a0.x += v0.x; a0.y += v0.y;
  }
  float2 b = *(const float2*)&brel[lane * 2];
  float2 o = *(const float2*)&xo[(size_t)node * 128 + lane * 2];
  float2 h;
  h.x = fmaxf(a0.x + a1.x + a2.x + a3.x + b.x + o.x, 0.f);
  h.y = fmaxf(a0.y + a1.y + a2.y + a3.y + b.y + o.y, 0.f);
  *(float2*)&hout[(size_t)node * 128 + lane * 2] = h;
}

// ---------------------------------------------------------------------------
// TopK pool 1 (512 -> 256 per graph)
// ---------------------------------------------------------------------------
__global__ __launch_bounds__(512) void topk1_kernel(
    const float* __restrict__ h1, const float* __restrict__ pw,
    float* __restrict__ xnew, int* __restrict__ map,
    float* __restrict__ x1p, float* __restrict__ score_out) {
  const int g = blockIdx.x, tid = threadIdx.x;
  __shared__ float sc[NPER];
  __shared__ int si[NPER];
  __shared__ float xn[K1 * 128];
  __shared__ float wsh[128];
  __shared__ float redm[4 * 128];
  __shared__ float reds[4 * 128];
  if (tid < 128) wsh[tid] = pw[tid];
  __syncthreads();
  float nrm = 0.f;
  for (int i = 0; i < 128; ++i) nrm += wsh[i] * wsh[i];
  const float innorm = 1.f / sqrtf(nrm);

  {
    const float4* hp = (const float4*)&h1[(size_t)(g * NPER + tid) * 128];
    float s = 0.f;
#pragma unroll 8
    for (int j = 0; j < 32; ++j) {
      float4 v = hp[j];
      s += v.x * wsh[j * 4] + v.y * wsh[j * 4 + 1] +
           v.z * wsh[j * 4 + 2] + v.w * wsh[j * 4 + 3];
    }
    s *= innorm;
    s = 1.f / (1.f + expf(-s));
    sc[tid] = s;
    si[tid] = tid;
  }

  // bitonic sort, descending score, ties -> lower index first (lax.top_k)
  for (int k = 2; k <= NPER; k <<= 1) {
    for (int j = k >> 1; j > 0; j >>= 1) {
      __syncthreads();
      int p = tid ^ j;
      if (p > tid) {
        float sa = sc[tid], sb = sc[p];
        int ia = si[tid], ib = si[p];
        bool before = (sb > sa) || (sb == sa && ib < ia);
        if (before == ((tid & k) == 0)) {
          sc[tid] = sb; sc[p] = sa; si[tid] = ib; si[p] = ia;
        }
      }
    }
  }
  __syncthreads();

  map[g * NPER + tid] = -1;
  if (tid < K1) score_out[g * K1 + tid] = sc[tid];
  __syncthreads();
  if (tid < K1) map[g * NPER + si[tid]] = g * K1 + tid;

  const int wave = tid >> 6, lane = tid & 63;
  for (int j = wave; j < K1; j += 8) {
    int idx = si[j];
    float s2 = sc[j];
    float2 v = *(const float2*)&h1[(size_t)(g * NPER + idx) * 128 + lane * 2];
    float2 o;
    o.x = v.x * s2;
    o.y = v.y * s2;
    *(float2*)&xnew[(size_t)(g * K1 + j) * 128 + lane * 2] = o;
    xn[j * 128 + lane * 2] = o.x;
    xn[j * 128 + lane * 2 + 1] = o.y;
  }
  __syncthreads();

  const int c = tid & 127, grp = tid >> 7;   // 4 groups
  float mx = -1e30f, sm = 0.f;
  for (int r = grp; r < K1; r += 4) {
    float v = xn[r * 128 + c];
    mx = fmaxf(mx, v);
    sm += v;
  }
  redm[grp * 128 + c] = mx;
  reds[grp * 128 + c] = sm;
  __syncthreads();
  if (tid < 128) {
    float m = fmaxf(fmaxf(redm[c], redm[128 + c]), fmaxf(redm[256 + c], redm[384 + c]));
    float su = reds[c] + reds[128 + c] + reds[256 + c] + reds[384 + c];
    x1p[g * 256 + tid] = m;
    x1p[g * 256 + 128 + tid] = su * (1.f / 256.f);
  }
}

// ---------------------------------------------------------------------------
// TopK pool 2 (256 -> 128 per graph): pools only.
// ---------------------------------------------------------------------------
__global__ __launch_bounds__(256) void topk2_kernel(
    const float* __restrict__ h2, const float* __restrict__ pw,
    float* __restrict__ x2p) {
  const int g = blockIdx.x, tid = threadIdx.x;
  __shared__ float sc[K1];
  __shared__ int si[K1];
  __shared__ float xn[K2 * 128];
  __shared__ float wsh[128];
  __shared__ float redm[2 * 128];
  __shared__ float reds[2 * 128];
  if (tid < 128) wsh[tid] = pw[tid];
  __syncthreads();
  float nrm = 0.f;
  for (int i = 0; i < 128; ++i) nrm += wsh[i] * wsh[i];
  const float innorm = 1.f / sqrtf(nrm);
  {
    const float4* hp = (const float4*)&h2[(size_t)(g * K1 + tid) * 128];
    float s = 0.f;
#pragma unroll 8
    for (int j = 0; j < 32; ++j) {
      float4 v = hp[j];
      s += v.x * wsh[j * 4] + v.y * wsh[j * 4 + 1] +
           v.z * wsh[j * 4 + 2] + v.w * wsh[j * 4 + 3];
    }
    s *= innorm;
    s = 1.f / (1.f + expf(-s));
    sc[tid] = s;
    si[tid] = tid;
  }
  for (int k = 2; k <= K1; k <<= 1) {
    for (int j = k >> 1; j > 0; j >>= 1) {
      __syncthreads();
      int p = tid ^ j;
      if (p > tid) {
        float sa = sc[tid], sb = sc[p];
        int ia = si[tid], ib = si[p];
        bool before = (sb > sa) || (sb == sa && ib < ia);
        if (before == ((tid & k) == 0)) {
          sc[tid] = sb; sc[p] = sa; si[tid] = ib; si[p] = ia;
        }
      }
    }
  }
  __syncthreads();
  const int wave = tid >> 6, lane = tid & 63;  // 4 waves
  for (int j = wave; j < K2; j += 4) {
    int idx = si[j];
    float s2 = sc[j];
    float2 v = *(const float2*)&h2[(size_t)(g * K1 + idx) * 128 + lane * 2];
    xn[j * 128 + lane * 2] = v.x * s2;
    xn[j * 128 + lane * 2 + 1] = v.y * s2;
  }
  __syncthreads();
  const int c = tid & 127, grp = tid >> 7;  // 2 groups
  float mx = -1e30f, sm = 0.f;
  for (int r = grp; r < K2; r += 2) {
    float v = xn[r * 128 + c];
    mx = fmaxf(mx, v);
    sm += v;
  }
  redm[grp * 128 + c] = mx;
  reds[grp * 128 + c] = sm;
  __syncthreads();
  if (tid < 128) {
    float m = fmaxf(redm[c], redm[128 + c]);
    float su = reds[c] + reds[128 + c];
    x2p[g * 256 + tid] = m;
    x2p[g * 256 + 128 + tid] = su * (1.f / 128.f);
  }
}

// ---------------------------------------------------------------------------
// Head
// ---------------------------------------------------------------------------
__global__ __launch_bounds__(128) void head_kernel(
    const float* __restrict__ x1p, const float* __restrict__ x2p,
    const float* __restrict__ lin1_w, const float* __restrict__ lin1_b,
    const float* __restrict__ bng, const float* __restrict__ bnb,
    const float* __restrict__ bnm, const float* __restrict__ bnv,
    const float* __restrict__ lin2_w, const float* __restrict__ lin2_b,
    const float* __restrict__ pool1_w, float* __restrict__ out) {
  const int g = blockIdx.x, tid = threadIdx.x;
  __shared__ float ge[256];
  __shared__ float z[128];
  __shared__ float lg[16];
  for (int i = tid; i < 256; i += 128) {
    float v = x1p[g * 256 + i] + x2p[g * 256 + i];
    ge[i] = v;
    out[2048 + g * 256 + i] = v;   // g_emb output
  }
  __syncthreads();
  float a = lin1_b[tid];
  for (int k = 0; k < 256; ++k) a += ge[k] * lin1_w[k * 128 + tid];
  a = fmaxf(a, 0.f);
  a = (a - bnm[tid]) * bng[tid] / sqrtf(bnv[tid] + 1e-5f) + bnb[tid];
  z[tid] = a;
  __syncthreads();
  if (tid < 16) {
    float o = lin2_b[tid];
    for (int k = 0; k < 128; ++k) o += z[k] * lin2_w[k * 16 + tid];
    lg[tid] = o;
  }
  __syncthreads();
  if (tid < 16) {
    float m = lg[0];
    for (int j = 1; j < 16; ++j) m = fmaxf(m, lg[j]);
    float ssum = 0.f;
    for (int j = 0; j < 16; ++j) ssum += expf(lg[j] - m);
    out[g * 16 + tid] = lg[tid] - m - logf(ssum);
  }
  if (g == 0 && tid < 128) out[34816 + tid] = pool1_w[tid];  // pool1_w output
}

// ---------------------------------------------------------------------------
extern "C" void kernel_launch(void* const* d_in, const int* in_sizes, int n_in,
                              void* d_out, int out_size, void* d_ws, size_t ws_size,
                              hipStream_t stream) {
  const float* x       = (const float*)d_in[0];
  const int*   ei      = (const int*)d_in[1];
  const float* w_rel1  = (const float*)d_in[3];
  const float* b_rel1  = (const float*)d_in[4];
  const float* w_root1 = (const float*)d_in[5];
  const float* pool1_w = (const float*)d_in[6];
  const float* w_rel2  = (const float*)d_in[7];
  const float* b_rel2  = (const float*)d_in[8];
  const float* w_root2 = (const float*)d_in[9];
  const float* pool2_w = (const float*)d_in[10];
  const float* lin1_w  = (const float*)d_in[11];
  const float* lin1_b  = (const float*)d_in[12];
  const float* bng     = (const float*)d_in[13];
  const float* bnb     = (const float*)d_in[14];
  const float* bnm     = (const float*)d_in[15];
  const float* bnv     = (const float*)d_in[16];
  const float* lin2_w  = (const float*)d_in[17];
  const float* lin2_b  = (const float*)d_in[18];
  const int* src = ei;
  const int* dst = ei + NEDGE;

  char* ws = (char*)d_ws;
  float* xr1  = (float*)(ws + 0);
  float* xoh1 = (float*)(ws + 33554432UL);
  float* xnew = (float*)(ws + 67108864UL);
  int*   eid  = (int*)  (ws + 67108864UL);
  int*   map  = (int*)  (ws + 83886080UL);
  int*   rowptr = (int*)(ws + 84148224UL);
  int*   cursor = (int*)(ws + 84410368UL);
  int*   deg  = (int*)  (ws + 84672512UL);
  float* x1p  = (float*)(ws + 84934656UL);
  float* x2p  = (float*)(ws + 85065728UL);
  short* wth  = (short*)(ws + 85196800UL);   // [256][K] bf16-hi bits
  short* wtl  = (short*)(ws + 85327872UL);   // [256][K] bf16-lo bits
  float* xr2  = (float*)(ws + 0);
  float* xo2  = (float*)(ws + 16777216UL);
  float* h2   = xoh1;
  float* out  = (float*)d_out;

  // ---- Layer 1 ----
  build_wt<<<dim3(256), dim3(256), 0, stream>>>(w_rel1, w_root1, wth, wtl, 256);
  gemm_mfma_dual<256><<<dim3(512), dim3(256), 0, stream>>>(x, wth, wtl, xr1, xoh1);
  hipMemsetAsync(deg, 0, NTOT * sizeof(int), stream);
  csr_count1<<<dim3(NEDGE / 512), dim3(512), 0, stream>>>(dst, deg);
  csr_scan<NPER><<<dim3(NG), dim3(NPER), 0, stream>>>(deg, rowptr, cursor);
  csr_fill1<<<dim3(NEDGE / 512), dim3(512), 0, stream>>>(src, dst, cursor, eid);
  agg_gather<<<dim3(NTOT / 8), dim3(512), 0, stream>>>(
      xr1, xoh1, b_rel1, rowptr, deg, eid, xoh1, NTOT);
  topk1_kernel<<<dim3(NG), dim3(512), 0, stream>>>(xoh1, pool1_w, xnew, map, x1p, out + 34944);

  // ---- Layer 2 ----
  build_wt<<<dim3(256), dim3(128), 0, stream>>>(w_rel2, w_root2, wth, wtl, 128);
  gemm_mfma_dual<128><<<dim3(256), dim3(256), 0, stream>>>(xnew, wth, wtl, xr2, xo2);
  hipMemsetAsync(deg, 0, NG * K1 * sizeof(int), stream);
  csr_count2<<<dim3(NEDGE / 512), dim3(512), 0, stream>>>(src, dst, map, deg);
  csr_scan<K1><<<dim3(NG), dim3(K1), 0, stream>>>(deg, rowptr, cursor);
  csr_fill2<<<dim3(NEDGE / 512), dim3(512), 0, stream>>>(src, dst, map, cursor, eid);
  agg_gather<<<dim3(NG * K1 / 8), dim3(512), 0, stream>>>(
      xr2, xo2, b_rel2, rowptr, deg, eid, h2, NG * K1);
  topk2_kernel<<<dim3(NG), dim3(K1), 0, stream>>>(h2, pool2_w, x2p);

  // ---- Head ----
  head_kernel<<<dim3(NG), dim3(128), 0, stream>>>(x1p, x2p, lin1_w, lin1_b,
      bng, bnb, bnm, bnv, lin2_w, lin2_b, pool1_w, out);
}

// Round 4
// 208.389 us; speedup vs baseline: 5.5320x; 1.4225x over previous
//
#include <hip/hip_runtime.h>
#include <cmath>

// Problem constants
#define NG    128       // graphs
#define NPER  512       // nodes per graph (layer 1)
#define NTOT  65536     // total nodes
#define NEDGE 1048576   // total edges
#define EPG   8192      // edges per graph
#define DD    128
#define K1    256       // kept nodes per graph after pool1
#define K2    128       // kept nodes per graph after pool2
#define SLOTS 56        // fixed edge-bucket slots per node (max degree ~40)

typedef float f32x4 __attribute__((ext_vector_type(4)));
typedef short short8 __attribute__((ext_vector_type(8)));

// 16B-chunk swizzle within a 64B row: keeps LDS writes AND reads bank-uniform
__device__ __forceinline__ int SW(int row, int c) { return (c ^ ((row >> 1) & 3)) * 8; }

__device__ __forceinline__ void bsplit(float v, short& h, short& l) {
  unsigned u = __builtin_bit_cast(unsigned, v);
  h = (short)(u >> 16);
  float lf = v - __builtin_bit_cast(float, u & 0xFFFF0000u);
  l = (short)(__builtin_bit_cast(unsigned, lf) >> 16);
}

// ---------------------------------------------------------------------------
// Prep: split W1|W2 (layer1, K=256) and W3|W4 (layer2, K=128) into bf16 hi/lo,
// k-tiled layout: [(k>>5)][n][k&31] contiguous per 256x32 tile. Zero cnt.
// ---------------------------------------------------------------------------
__global__ __launch_bounds__(256) void build_wt_all(
    const float* __restrict__ W1, const float* __restrict__ W2,
    const float* __restrict__ W3, const float* __restrict__ W4,
    short* __restrict__ h1, short* __restrict__ l1,
    short* __restrict__ h2, short* __restrict__ l2, int* __restrict__ cnt) {
  const int n = blockIdx.x, k = threadIdx.x;
  cnt[n * 256 + k] = 0;
  {
    float w = (n < 128) ? W1[k * 128 + n] : W2[k * 128 + (n - 128)];
    short h, l; bsplit(w, h, l);
    int off = ((k >> 5) * 256 + n) * 32 + (k & 31);
    h1[off] = h; l1[off] = l;
  }
  if (k < 128) {
    float w = (n < 128) ? W3[k * 128 + n] : W4[k * 128 + (n - 128)];
    short h, l; bsplit(w, h, l);
    int off = ((k >> 5) * 256 + n) * 32 + (k & 31);
    h2[off] = h; l2[off] = l;
  }
}

// ---------------------------------------------------------------------------
// Split-bf16 MFMA dual GEMM, register-double-buffered staging.
// A [M,K] f32; wt tiled [K/32][256][32] bf16 hi/lo. Tile 128M x 256N, BK=32.
// ---------------------------------------------------------------------------
template<int K>
__global__ __launch_bounds__(256) void gemm_mfma_dual(
    const float* __restrict__ A,
    const short* __restrict__ wth, const short* __restrict__ wtl,
    float* __restrict__ C1, float* __restrict__ C2) {
  __shared__ short Ah[128 * 32], Al[128 * 32];     // 8 KB each
  __shared__ short Wh[256 * 32], Wl[256 * 32];     // 16 KB each
  const int tid = threadIdx.x, lane = tid & 63, wid = tid >> 6;
  const int wm = (wid >> 1) * 64, wn = (wid & 1) * 128;
  const size_t row0 = (size_t)blockIdx.x * 128;
  const int l15 = lane & 15, cq = lane >> 4;
  const int ar = tid >> 1, cb = (tid & 1) * 2;     // A: row, first chunk
  constexpr int NT = K / 32;

  const float* ap = A + (row0 + ar) * K + cb * 8;

  float4 pa0, pa1, pa2, pa3;
  int4 pwh0, pwh1, pwh2, pwh3, pwl0, pwl1, pwl2, pwl3;

#define LOAD_A(t) { const float4* p = (const float4*)(ap + (t) * 32); \
    pa0 = p[0]; pa1 = p[1]; pa2 = p[2]; pa3 = p[3]; }
#define LOAD_W(t) { const int4* ph = (const int4*)(wth + (size_t)(t) * 8192 + tid * 32); \
    const int4* pl = (const int4*)(wtl + (size_t)(t) * 8192 + tid * 32); \
    pwh0 = ph[0]; pwh1 = ph[1]; pwh2 = ph[2]; pwh3 = ph[3]; \
    pwl0 = pl[0]; pwl1 = pl[1]; pwl2 = pl[2]; pwl3 = pl[3]; }
#define STORE_ALL() { \
    float f[16] = {pa0.x, pa0.y, pa0.z, pa0.w, pa1.x, pa1.y, pa1.z, pa1.w, \
                   pa2.x, pa2.y, pa2.z, pa2.w, pa3.x, pa3.y, pa3.z, pa3.w}; \
    short8 h0, h1v, l0v, l1v; \
    _Pragma("unroll") \
    for (int i = 0; i < 8; ++i) { \
      short hh, ll; bsplit(f[i], hh, ll); h0[i] = hh; l0v[i] = ll; \
      bsplit(f[8 + i], hh, ll); h1v[i] = hh; l1v[i] = ll; } \
    *(short8*)&Ah[ar * 32 + SW(ar, cb)]     = h0; \
    *(short8*)&Ah[ar * 32 + SW(ar, cb + 1)] = h1v; \
    *(short8*)&Al[ar * 32 + SW(ar, cb)]     = l0v; \
    *(short8*)&Al[ar * 32 + SW(ar, cb + 1)] = l1v; \
    *(int4*)&Wh[tid * 32 + SW(tid, 0)] = pwh0; \
    *(int4*)&Wh[tid * 32 + SW(tid, 1)] = pwh1; \
    *(int4*)&Wh[tid * 32 + SW(tid, 2)] = pwh2; \
    *(int4*)&Wh[tid * 32 + SW(tid, 3)] = pwh3; \
    *(int4*)&Wl[tid * 32 + SW(tid, 0)] = pwl0; \
    *(int4*)&Wl[tid * 32 + SW(tid, 1)] = pwl1; \
    *(int4*)&Wl[tid * 32 + SW(tid, 2)] = pwl2; \
    *(int4*)&Wl[tid * 32 + SW(tid, 3)] = pwl3; }

  f32x4 acc[4][8];
#pragma unroll
  for (int mf = 0; mf < 4; ++mf)
#pragma unroll
    for (int nf = 0; nf < 8; ++nf) acc[mf][nf] = (f32x4){0.f, 0.f, 0.f, 0.f};

  LOAD_A(0); LOAD_W(0);
  STORE_ALL();
  __syncthreads();
  if (NT > 1) { LOAD_A(1); LOAD_W(1); }   // overlaps compute(0)

  for (int t = 0; t < NT; ++t) {
    short8 bh[8], bl[8];
#pragma unroll
    for (int nf = 0; nf < 8; ++nf) {
      int rn = wn + nf * 16 + l15;
      bh[nf] = *(const short8*)&Wh[rn * 32 + SW(rn, cq)];
      bl[nf] = *(const short8*)&Wl[rn * 32 + SW(rn, cq)];
    }
#pragma unroll
    for (int mf = 0; mf < 4; ++mf) {
      int rm = wm + mf * 16 + l15;
      short8 ah = *(const short8*)&Ah[rm * 32 + SW(rm, cq)];
      short8 al = *(const short8*)&Al[rm * 32 + SW(rm, cq)];
#pragma unroll
      for (int nf = 0; nf < 8; ++nf) {
        acc[mf][nf] = __builtin_amdgcn_mfma_f32_16x16x32_bf16(ah, bh[nf], acc[mf][nf], 0, 0, 0);
        acc[mf][nf] = __builtin_amdgcn_mfma_f32_16x16x32_bf16(ah, bl[nf], acc[mf][nf], 0, 0, 0);
        acc[mf][nf] = __builtin_amdgcn_mfma_f32_16x16x32_bf16(al, bh[nf], acc[mf][nf], 0, 0, 0);
      }
    }
    if (t + 1 < NT) {
      __syncthreads();          // all waves done reading LDS (also drains t+1 loads)
      STORE_ALL();              // stage t+1 regs -> LDS
      __syncthreads();          // writes visible
      if (t + 2 < NT) { LOAD_A(t + 2); LOAD_W(t + 2); }  // overlap compute(t+1)
    }
  }
#undef LOAD_A
#undef LOAD_W
#undef STORE_ALL

  float* Cb = (wn == 0) ? C1 : C2;
#pragma unroll
  for (int mf = 0; mf < 4; ++mf) {
    size_t rbase = row0 + wm + mf * 16 + (lane >> 4) * 4;
#pragma unroll
    for (int nf = 0; nf < 8; ++nf) {
      int c = nf * 16 + l15;
#pragma unroll
      for (int r = 0; r < 4; ++r)
        Cb[(rbase + r) * 128 + c] = acc[mf][nf][r];
    }
  }
}

// ---------------------------------------------------------------------------
// Bucketed edge fill (count+fill in one pass; SLOTS fixed per node)
// ---------------------------------------------------------------------------
__global__ __launch_bounds__(512) void bucket_fill1(
    const int* __restrict__ src, const int* __restrict__ dst,
    int* __restrict__ cnt, int* __restrict__ eid) {
  int e = blockIdx.x * 512 + threadIdx.x;
  int d = dst[e];
  int pos = atomicAdd(&cnt[d], 1);
  eid[d * SLOTS + pos] = src[e];
}

__global__ __launch_bounds__(512) void bucket_fill2(
    const int* __restrict__ src, const int* __restrict__ dst,
    const int* __restrict__ map, int* __restrict__ cnt, int* __restrict__ eid) {
  int e = blockIdx.x * 512 + threadIdx.x;
  int ms = map[src[e]], md = map[dst[e]];
  if ((ms | md) >= 0) {
    int pos = atomicAdd(&cnt[md], 1);
    eid[md * SLOTS + pos] = ms;
  }
}

// ---------------------------------------------------------------------------
// Gather aggregation: one wave per node, 2 edges per load instr (float4 lanes).
// XCD-swizzled block mapping (graph's blocks share one L2).
// ---------------------------------------------------------------------------
template<int CPX>
__global__ __launch_bounds__(512) void agg_gather(
    const float* __restrict__ xr, const float* __restrict__ xo,
    const float* __restrict__ brel, const int* __restrict__ cnt,
    const int* __restrict__ eid, float* __restrict__ hout) {
  const int bid = blockIdx.x;
  const int lb = (bid & 7) * CPX + (bid >> 3);
  const int wave = threadIdx.x >> 6, lane = threadIdx.x & 63;
  const int node = lb * 8 + wave;
  const int dg = cnt[node];
  const int base = node * SLOTS;
  const int half = lane >> 5, l32 = lane & 31;
  f32x4 a0 = {0.f, 0.f, 0.f, 0.f}, a1 = a0, a2 = a0, a3 = a0;
  int j = 0;
  for (; j + 8 <= dg; j += 8) {
    int e0 = eid[base + j + 0 + half];
    int e1 = eid[base + j + 2 + half];
    int e2 = eid[base + j + 4 + half];
    int e3 = eid[base + j + 6 + half];
    a0 += *(const f32x4*)&xr[(size_t)e0 * 128 + l32 * 4];
    a1 += *(const f32x4*)&xr[(size_t)e1 * 128 + l32 * 4];
    a2 += *(const f32x4*)&xr[(size_t)e2 * 128 + l32 * 4];
    a3 += *(const f32x4*)&xr[(size_t)e3 * 128 + l32 * 4];
  }
  for (; j + 2 <= dg; j += 2) {
    int e = eid[base + j + half];
    a0 += *(const f32x4*)&xr[(size_t)e * 128 + l32 * 4];
  }
  if (j < dg && half == 0) {
    int e = eid[base + j];
    a1 += *(const f32x4*)&xr[(size_t)e * 128 + l32 * 4];
  }
  f32x4 s = a0 + a1 + a2 + a3;
  s[0] += __shfl_xor(s[0], 32);
  s[1] += __shfl_xor(s[1], 32);
  s[2] += __shfl_xor(s[2], 32);
  s[3] += __shfl_xor(s[3], 32);
  if (half == 0) {
    f32x4 b = *(const f32x4*)&brel[l32 * 4];
    f32x4 o = *(const f32x4*)&xo[(size_t)node * 128 + l32 * 4];
    f32x4 h;
#pragma unroll
    for (int i = 0; i < 4; ++i) h[i] = fmaxf(s[i] + b[i] + o[i], 0.f);
    *(f32x4*)&hout[(size_t)node * 128 + l32 * 4] = h;
  }
}

// ---------------------------------------------------------------------------
// TopK pool 1 (512 -> 256 per graph); also zeroes cnt for layer 2.
// ---------------------------------------------------------------------------
__global__ __launch_bounds__(512) void topk1_kernel(
    const float* __restrict__ h1, const float* __restrict__ pw,
    float* __restrict__ xnew, int* __restrict__ map, int* __restrict__ cnt,
    float* __restrict__ x1p, float* __restrict__ score_out) {
  const int g = blockIdx.x, tid = threadIdx.x;
  __shared__ float sc[NPER];
  __shared__ int si[NPER];
  __shared__ float xn[K1 * 128];
  __shared__ float wsh[128];
  __shared__ float redm[4 * 128];
  __shared__ float reds[4 * 128];
  {
    int gt = g * 512 + tid;
    if (gt < NG * K1) cnt[gt] = 0;   // zero layer-2 buckets
  }
  if (tid < 128) wsh[tid] = pw[tid];
  __syncthreads();
  float nrm = 0.f;
  for (int i = 0; i < 128; ++i) nrm += wsh[i] * wsh[i];
  const float innorm = 1.f / sqrtf(nrm);

  {
    const float4* hp = (const float4*)&h1[(size_t)(g * NPER + tid) * 128];
    float s = 0.f;
#pragma unroll 8
    for (int j = 0; j < 32; ++j) {
      float4 v = hp[j];
      s += v.x * wsh[j * 4] + v.y * wsh[j * 4 + 1] +
           v.z * wsh[j * 4 + 2] + v.w * wsh[j * 4 + 3];
    }
    s *= innorm;
    s = 1.f / (1.f + expf(-s));
    sc[tid] = s;
    si[tid] = tid;
  }

  // bitonic sort, descending score, ties -> lower index first (lax.top_k)
  for (int k = 2; k <= NPER; k <<= 1) {
    for (int j = k >> 1; j > 0; j >>= 1) {
      __syncthreads();
      int p = tid ^ j;
      if (p > tid) {
        float sa = sc[tid], sb = sc[p];
        int ia = si[tid], ib = si[p];
        bool before = (sb > sa) || (sb == sa && ib < ia);
        if (before == ((tid & k) == 0)) {
          sc[tid] = sb; sc[p] = sa; si[tid] = ib; si[p] = ia;
        }
      }
    }
  }
  __syncthreads();

  map[g * NPER + tid] = -1;
  if (tid < K1) score_out[g * K1 + tid] = sc[tid];
  __syncthreads();
  if (tid < K1) map[g * NPER + si[tid]] = g * K1 + tid;

  const int wave = tid >> 6, lane = tid & 63;
  for (int j = wave; j < K1; j += 8) {
    int idx = si[j];
    float s2 = sc[j];
    float2 v = *(const float2*)&h1[(size_t)(g * NPER + idx) * 128 + lane * 2];
    float2 o;
    o.x = v.x * s2;
    o.y = v.y * s2;
    *(float2*)&xnew[(size_t)(g * K1 + j) * 128 + lane * 2] = o;
    xn[j * 128 + lane * 2] = o.x;
    xn[j * 128 + lane * 2 + 1] = o.y;
  }
  __syncthreads();

  const int c = tid & 127, grp = tid >> 7;   // 4 groups
  float mx = -1e30f, sm = 0.f;
  for (int r = grp; r < K1; r += 4) {
    float v = xn[r * 128 + c];
    mx = fmaxf(mx, v);
    sm += v;
  }
  redm[grp * 128 + c] = mx;
  reds[grp * 128 + c] = sm;
  __syncthreads();
  if (tid < 128) {
    float m = fmaxf(fmaxf(redm[c], redm[128 + c]), fmaxf(redm[256 + c], redm[384 + c]));
    float su = reds[c] + reds[128 + c] + reds[256 + c] + reds[384 + c];
    x1p[g * 256 + tid] = m;
    x1p[g * 256 + 128 + tid] = su * (1.f / 256.f);
  }
}

// ---------------------------------------------------------------------------
// TopK pool 2 (256 -> 128) fused with classifier head.
// ---------------------------------------------------------------------------
__global__ __launch_bounds__(256) void topk2_head_kernel(
    const float* __restrict__ h2, const float* __restrict__ pw,
    const float* __restrict__ x1p,
    const float* __restrict__ lin1_w, const float* __restrict__ lin1_b,
    const float* __restrict__ bng, const float* __restrict__ bnb,
    const float* __restrict__ bnm, const float* __restrict__ bnv,
    const float* __restrict__ lin2_w, const float* __restrict__ lin2_b,
    const float* __restrict__ pool1_w, float* __restrict__ out) {
  const int g = blockIdx.x, tid = threadIdx.x;
  __shared__ float sc[K1];
  __shared__ int si[K1];
  __shared__ float xn[K2 * 128];
  __shared__ float wsh[128];
  __shared__ float redm[2 * 128];
  __shared__ float reds[2 * 128];
  __shared__ float ge[256];
  __shared__ float zz[128];
  __shared__ float lg[16];
  if (tid < 128) wsh[tid] = pw[tid];
  __syncthreads();
  float nrm = 0.f;
  for (int i = 0; i < 128; ++i) nrm += wsh[i] * wsh[i];
  const float innorm = 1.f / sqrtf(nrm);
  {
    const float4* hp = (const float4*)&h2[(size_t)(g * K1 + tid) * 128];
    float s = 0.f;
#pragma unroll 8
    for (int j = 0; j < 32; ++j) {
      float4 v = hp[j];
      s += v.x * wsh[j * 4] + v.y * wsh[j * 4 + 1] +
           v.z * wsh[j * 4 + 2] + v.w * wsh[j * 4 + 3];
    }
    s *= innorm;
    s = 1.f / (1.f + expf(-s));
    sc[tid] = s;
    si[tid] = tid;
  }
  for (int k = 2; k <= K1; k <<= 1) {
    for (int j = k >> 1; j > 0; j >>= 1) {
      __syncthreads();
      int p = tid ^ j;
      if (p > tid) {
        float sa = sc[tid], sb = sc[p];
        int ia = si[tid], ib = si[p];
        bool before = (sb > sa) || (sb == sa && ib < ia);
        if (before == ((tid & k) == 0)) {
          sc[tid] = sb; sc[p] = sa; si[tid] = ib; si[p] = ia;
        }
      }
    }
  }
  __syncthreads();
  const int wave = tid >> 6, lane = tid & 63;  // 4 waves
  for (int j = wave; j < K2; j += 4) {
    int idx = si[j];
    float s2 = sc[j];
    float2 v = *(const float2*)&h2[(size_t)(g * K1 + idx) * 128 + lane * 2];
    xn[j * 128 + lane * 2] = v.x * s2;
    xn[j * 128 + lane * 2 + 1] = v.y * s2;
  }
  __syncthreads();
  const int c = tid & 127, grp = tid >> 7;  // 2 groups
  float mx = -1e30f, sm = 0.f;
  for (int r = grp; r < K2; r += 2) {
    float v = xn[r * 128 + c];
    mx = fmaxf(mx, v);
    sm += v;
  }
  redm[grp * 128 + c] = mx;
  reds[grp * 128 + c] = sm;
  __syncthreads();
  // ---- head ----
  if (tid < 128) {
    float m = fmaxf(redm[c], redm[128 + c]);
    float su = (reds[c] + reds[128 + c]) * (1.f / 128.f);
    float v1 = x1p[g * 256 + tid] + m;
    float v2 = x1p[g * 256 + 128 + tid] + su;
    ge[tid] = v1;
    ge[128 + tid] = v2;
    out[2048 + g * 256 + tid] = v1;          // g_emb output
    out[2048 + g * 256 + 128 + tid] = v2;
  }
  __syncthreads();
  if (tid < 128) {
    float a = lin1_b[tid];
    for (int k = 0; k < 256; ++k) a += ge[k] * lin1_w[k * 128 + tid];
    a = fmaxf(a, 0.f);
    a = (a - bnm[tid]) * bng[tid] / sqrtf(bnv[tid] + 1e-5f) + bnb[tid];
    zz[tid] = a;
  }
  __syncthreads();
  if (tid < 16) {
    float o = lin2_b[tid];
    for (int k = 0; k < 128; ++k) o += zz[k] * lin2_w[k * 16 + tid];
    lg[tid] = o;
  }
  __syncthreads();
  if (tid < 16) {
    float m = lg[0];
    for (int j = 1; j < 16; ++j) m = fmaxf(m, lg[j]);
    float ssum = 0.f;
    for (int j = 0; j < 16; ++j) ssum += expf(lg[j] - m);
    out[g * 16 + tid] = lg[tid] - m - logf(ssum);
  }
  if (g == 0 && tid < 128) out[34816 + tid] = pool1_w[tid];  // pool1_w output
}

// ---------------------------------------------------------------------------
extern "C" void kernel_launch(void* const* d_in, const int* in_sizes, int n_in,
                              void* d_out, int out_size, void* d_ws, size_t ws_size,
                              hipStream_t stream) {
  const float* x       = (const float*)d_in[0];
  const int*   ei      = (const int*)d_in[1];
  const float* w_rel1  = (const float*)d_in[3];
  const float* b_rel1  = (const float*)d_in[4];
  const float* w_root1 = (const float*)d_in[5];
  const float* pool1_w = (const float*)d_in[6];
  const float* w_rel2  = (const float*)d_in[7];
  const float* b_rel2  = (const float*)d_in[8];
  const float* w_root2 = (const float*)d_in[9];
  const float* pool2_w = (const float*)d_in[10];
  const float* lin1_w  = (const float*)d_in[11];
  const float* lin1_b  = (const float*)d_in[12];
  const float* bng     = (const float*)d_in[13];
  const float* bnb     = (const float*)d_in[14];
  const float* bnm     = (const float*)d_in[15];
  const float* bnv     = (const float*)d_in[16];
  const float* lin2_w  = (const float*)d_in[17];
  const float* lin2_b  = (const float*)d_in[18];
  const int* src = ei;
  const int* dst = ei + NEDGE;

  char* ws = (char*)d_ws;
  // Layout (bytes):
  //  [0,32M)    xr1 [65536,128]          ; layer2: xr2 (16M) + xo2 @16M
  //  [32M,64M)  xo1/h1 in place          ; layer2: h2 (first 16M)
  //  [64M,80M)  eid1 (14.7M) -> xnew (16M) -> eid2 (7.4M)  (time-multiplexed)
  //  [80M,..)   map, cnt, x1p, wth1, wtl1, wth2, wtl2
  float* xr1  = (float*)(ws + 0);
  float* xoh1 = (float*)(ws + 33554432UL);
  float* xnew = (float*)(ws + 67108864UL);
  int*   eid  = (int*)  (ws + 67108864UL);
  int*   map  = (int*)  (ws + 83886080UL);
  int*   cnt  = (int*)  (ws + 84148224UL);
  float* x1p  = (float*)(ws + 84410368UL);
  short* wth1 = (short*)(ws + 84541440UL);
  short* wtl1 = (short*)(ws + 84672512UL);
  short* wth2 = (short*)(ws + 84803584UL);
  short* wtl2 = (short*)(ws + 84869120UL);
  float* xr2  = (float*)(ws + 0);
  float* xo2  = (float*)(ws + 16777216UL);
  float* h2   = xoh1;
  float* out  = (float*)d_out;

  // ---- Layer 1 ----
  build_wt_all<<<dim3(256), dim3(256), 0, stream>>>(
      w_rel1, w_root1, w_rel2, w_root2, wth1, wtl1, wth2, wtl2, cnt);
  gemm_mfma_dual<256><<<dim3(512), dim3(256), 0, stream>>>(x, wth1, wtl1, xr1, xoh1);
  bucket_fill1<<<dim3(NEDGE / 512), dim3(512), 0, stream>>>(src, dst, cnt, eid);
  agg_gather<1024><<<dim3(8192), dim3(512), 0, stream>>>(xr1, xoh1, b_rel1, cnt, eid, xoh1);
  topk1_kernel<<<dim3(NG), dim3(512), 0, stream>>>(xoh1, pool1_w, xnew, map, cnt, x1p, out + 34944);

  // ---- Layer 2 ----
  gemm_mfma_dual<128><<<dim3(256), dim3(256), 0, stream>>>(xnew, wth2, wtl2, xr2, xo2);
  bucket_fill2<<<dim3(NEDGE / 512), dim3(512), 0, stream>>>(src, dst, map, cnt, eid);
  agg_gather<512><<<dim3(4096), dim3(512), 0, stream>>>(xr2, xo2, b_rel2, cnt, eid, h2);

  // ---- TopK2 + head ----
  topk2_head_kernel<<<dim3(NG), dim3(K1), 0, stream>>>(h2, pool2_w, x1p,
      lin1_w, lin1_b, bng, bnb, bnm, bnv, lin2_w, lin2_b, pool1_w, out);
}